// Round 1
// baseline (163.111 us; speedup 1.0000x reference)
//
#include <hip/hip_runtime.h>

typedef unsigned short u16;
typedef __attribute__((ext_vector_type(8))) __bf16 bf16x8;
typedef __attribute__((ext_vector_type(4))) float f32x4;

#define LOG2E 1.44269504088896f

__device__ __forceinline__ u16 f2bf(float f) {
  union { float f; unsigned u; } c; c.f = f;
  unsigned u = c.u;
  return (u16)((u + 0x7fffu + ((u >> 16) & 1u)) >> 16);
}

__device__ __forceinline__ void load_lds16(const void* g, void* l) {
  __builtin_amdgcn_global_load_lds((const __attribute__((address_space(1))) unsigned int*)g,
                                   (__attribute__((address_space(3))) unsigned int*)l, 16, 0, 0);
}

// ---------------- cast f32 -> bf16 ----------------
__global__ void cast_bf16_kernel(const float* __restrict__ in, u16* __restrict__ out, int n4) {
  int stride = gridDim.x * blockDim.x;
  for (int i = blockIdx.x * blockDim.x + threadIdx.x; i < n4; i += stride) {
    float4 v = ((const float4*)in)[i];
    ushort4 o;
    o.x = f2bf(v.x); o.y = f2bf(v.y); o.z = f2bf(v.z); o.w = f2bf(v.w);
    ((ushort4*)out)[i] = o;
  }
}

// ---------------- transpose + cast: in (R x C) f32 -> out (C x R) bf16 ----------------
__global__ void transpose_cast_kernel(const float* __restrict__ in, u16* __restrict__ out, int R, int C) {
  __shared__ float tile[32][33];
  int c0 = blockIdx.x * 32, r0 = blockIdx.y * 32;
  int tx = threadIdx.x, ty = threadIdx.y; // (32,8)
#pragma unroll
  for (int i = 0; i < 4; ++i)
    tile[ty + 8 * i][tx] = in[(size_t)(r0 + ty + 8 * i) * C + c0 + tx];
  __syncthreads();
#pragma unroll
  for (int i = 0; i < 4; ++i)
    out[(size_t)(c0 + ty + 8 * i) * R + r0 + tx] = f2bf(tile[tx][ty + 8 * i]);
}

// ---------------- 128x128 bf16 B^T GEMM body (BK=64, swizzled LDS) ----------------
__device__ __forceinline__ void gemm128_body(const u16* A, const u16* Bt, float* C,
                                             int N, int K, u16* As, u16* Bs) {
  int tid = threadIdx.x;
  int w = tid >> 6, l = tid & 63;
  int g = l >> 4, lr = l & 15;
  int m0 = blockIdx.x * 128, n0 = blockIdx.y * 128;
  int wr = w >> 1, wc = w & 1;
  f32x4 acc[4][4];
#pragma unroll
  for (int m = 0; m < 4; ++m)
#pragma unroll
    for (int n = 0; n < 4; ++n) acc[m][n] = (f32x4){0.f, 0.f, 0.f, 0.f};

  for (int k0 = 0; k0 < K; k0 += 64) {
#pragma unroll
    for (int rnd = 0; rnd < 4; ++rnd) {
      int bidx = rnd * 4096 + w * 1024 + l * 16;
      int row = bidx >> 7, colb = bidx & 127;
      int scol = colb ^ ((row & 7) << 4);
      load_lds16((const char*)A + ((size_t)(m0 + row) * K + k0) * 2 + scol,
                 (char*)As + rnd * 4096 + w * 1024);
      load_lds16((const char*)Bt + ((size_t)(n0 + row) * K + k0) * 2 + scol,
                 (char*)Bs + rnd * 4096 + w * 1024);
    }
    __syncthreads();
    bf16x8 af[4][2], bfr[4][2];
#pragma unroll
    for (int m = 0; m < 4; ++m) {
      int ra = wr * 64 + m * 16 + lr;
      int rb = wc * 64 + m * 16 + lr;
#pragma unroll
      for (int kf = 0; kf < 2; ++kf) {
        af[m][kf]  = *(const bf16x8*)((const char*)As + ra * 128 + ((kf * 64 + g * 16) ^ ((ra & 7) << 4)));
        bfr[m][kf] = *(const bf16x8*)((const char*)Bs + rb * 128 + ((kf * 64 + g * 16) ^ ((rb & 7) << 4)));
      }
    }
#pragma unroll
    for (int m = 0; m < 4; ++m)
#pragma unroll
      for (int n = 0; n < 4; ++n) {
        acc[m][n] = __builtin_amdgcn_mfma_f32_16x16x32_bf16(af[m][0], bfr[n][0], acc[m][n], 0, 0, 0);
        acc[m][n] = __builtin_amdgcn_mfma_f32_16x16x32_bf16(af[m][1], bfr[n][1], acc[m][n], 0, 0, 0);
      }
    __syncthreads();
  }
#pragma unroll
  for (int m = 0; m < 4; ++m)
#pragma unroll
    for (int n = 0; n < 4; ++n) {
      int row = m0 + wr * 64 + m * 16 + g * 4;
      int col = n0 + wc * 64 + n * 16 + lr;
#pragma unroll
      for (int r = 0; r < 4; ++r)
        C[(size_t)(row + r) * N + col] = acc[m][n][r];
    }
}

__global__ __launch_bounds__(256, 2) void gemm_qkv_kernel(const u16* xb, const u16* eb,
                                                          const u16* WqT, const u16* WkT, const u16* WvT,
                                                          float* qr, float* kr, float* vr) {
  __shared__ __align__(16) u16 As[128 * 64];
  __shared__ __align__(16) u16 Bs[128 * 64];
  int z = blockIdx.z;
  const u16* A; const u16* Bt; float* C; int N;
  if (z == 0)      { A = xb; Bt = WqT; C = qr; N = 1024; }
  else if (z == 1) { A = eb; Bt = WkT; C = kr; N = 512; }
  else             { A = eb; Bt = WvT; C = vr; N = 512; }
  if ((int)blockIdx.y * 128 >= N) return;
  gemm128_body(A, Bt, C, N, 1024, As, Bs);
}

__global__ __launch_bounds__(256, 2) void gemm_out_kernel(const u16* Yb, const u16* WoT, float* out) {
  __shared__ __align__(16) u16 As[128 * 64];
  __shared__ __align__(16) u16 Bs[128 * 64];
  gemm128_body(Yb, WoT, out, 1024, 1024, As, Bs);
}

// ---------------- Q/K epilogue: l2norm + scale + rope + store (B,heads,T,64) bf16 ----------------
__global__ void epilogue_qk_kernel(const float* __restrict__ raw, const float* __restrict__ scale,
                                   const float* __restrict__ freqs, u16* __restrict__ out,
                                   int hshift, float final_scale) {
  int nheads = 1 << hshift;
  int unit = blockIdx.x * 4 + (threadIdx.x >> 6);
  int lane = threadIdx.x & 63;
  int hd = unit & (nheads - 1);
  int row = unit >> hshift;        // b*1024 + t
  int t = row & 1023;
  int b = row >> 10;
  float v = raw[(size_t)row * (nheads * 64) + hd * 64 + lane];
  float ss = v * v;
#pragma unroll
  for (int d = 1; d < 64; d <<= 1) ss += __shfl_xor(ss, d);
  float inv = 1.0f / fmaxf(sqrtf(ss), 1e-12f);
  v = v * inv * scale[lane];
  float f = (lane < 32) ? freqs[t * 32 + lane] : 0.0f;
  float sn, cs;
  sincosf(f, &sn, &cs);
  float partner = __shfl_xor(v, 1);
  float rot = (lane & 1) ? partner : -partner;
  float vr = v * cs + rot * sn;
  if (lane < 32) v = vr;
  v *= final_scale;
  out[(((size_t)b * nheads + hd) * 1024 + t) * 64 + lane] = f2bf(v);
}

// ---------------- V epilogue: rope + store transposed (B,KV,D,T) bf16 ----------------
__global__ void epilogue_v_kernel(const float* __restrict__ v_raw, const float* __restrict__ freqs,
                                  u16* __restrict__ Vt) {
  __shared__ __align__(16) u16 tile[64][72];
  int blk = blockIdx.x;
  int t0 = (blk & 15) * 64;
  int kvg = blk >> 4;            // b*8 + kv
  int kvv = kvg & 7;
  int bb = kvg >> 3;
  int tid = threadIdx.x;
  int tl = tid >> 2;             // token local 0..63
  int dq = (tid & 3) * 16;       // dim base
  int t = t0 + tl;
  const float* src = v_raw + ((size_t)(bb * 1024 + t)) * 512 + kvv * 64 + dq;
  float x[16];
#pragma unroll
  for (int i = 0; i < 4; ++i) {
    float4 q = *(const float4*)(src + i * 4);
    x[i * 4 + 0] = q.x; x[i * 4 + 1] = q.y; x[i * 4 + 2] = q.z; x[i * 4 + 3] = q.w;
  }
  if (dq < 32) {
#pragma unroll
    for (int j = 0; j < 8; ++j) {
      int d = dq + 2 * j;
      float f = freqs[t * 32 + d];
      float sn, cs; sincosf(f, &sn, &cs);
      float e = x[2 * j], o = x[2 * j + 1];
      x[2 * j]     = e * cs - o * sn;
      x[2 * j + 1] = o * cs + e * sn;
    }
  }
#pragma unroll
  for (int i = 0; i < 16; ++i) tile[dq + i][tl] = f2bf(x[i]);
  __syncthreads();
#pragma unroll
  for (int rnd = 0; rnd < 2; ++rnd) {
    int chunk = rnd * 256 + tid;
    int drow = chunk >> 3, c8 = chunk & 7;
    bf16x8 val = *(const bf16x8*)((const char*)&tile[0][0] + drow * 144 + c8 * 16);
    *(bf16x8*)(Vt + ((size_t)kvg * 64 + drow) * 1024 + t0 + c8 * 8) = val;
  }
}

// ---------------- flash attention with bias + causal ----------------
__global__ __launch_bounds__(256, 2) void attn_kernel(const u16* __restrict__ Qb, const u16* __restrict__ Kb,
                                                      const u16* __restrict__ Vtb, const float* __restrict__ bias,
                                                      u16* __restrict__ Yb) {
  __shared__ __align__(16) u16 Ks[64 * 64];
  __shared__ __align__(16) u16 Vs[64 * 64];
  __shared__ __align__(16) u16 Ps[4][16 * 72];
  int tid = threadIdx.x;
  int w = tid >> 6, l = tid & 63;
  int g = l >> 4, lr = l & 15;
  int q0 = blockIdx.x * 64;
  int bh = blockIdx.y;
  int b = bh >> 4, h = bh & 15, kv = h & 7;

  const u16* Qrow = Qb + ((size_t)(b * 16 + h) * 1024 + q0 + w * 16 + lr) * 64;
  bf16x8 aq0 = *(const bf16x8*)(Qrow + g * 8);
  bf16x8 aq1 = *(const bf16x8*)(Qrow + 32 + g * 8);
  const u16* Kg = Kb + (size_t)(b * 8 + kv) * 1024 * 64;
  const u16* Vg = Vtb + (size_t)(b * 8 + kv) * 64 * 1024;
  const float* biasg = bias + (size_t)h * 1024 * 1024;

  float mrow[4], lsum[4];
  f32x4 oacc[4];
#pragma unroll
  for (int r = 0; r < 4; ++r) { mrow[r] = -1e30f; lsum[r] = 0.f; }
#pragma unroll
  for (int df = 0; df < 4; ++df) oacc[df] = (f32x4){0.f, 0.f, 0.f, 0.f};
  int rq[4];
#pragma unroll
  for (int r = 0; r < 4; ++r) rq[r] = q0 + w * 16 + g * 4 + r;

  for (int t0 = 0; t0 <= q0; t0 += 64) {
    // stage K tile (64 keys x 64 dims) and V^T tile (64 dims x 64 keys), XOR-swizzled
#pragma unroll
    for (int rnd = 0; rnd < 2; ++rnd) {
      int bidx = rnd * 4096 + w * 1024 + l * 16;
      int row = bidx >> 7, colb = bidx & 127;
      int scol = colb ^ ((row & 7) << 4);
      load_lds16((const char*)Kg + (size_t)(t0 + row) * 128 + scol, (char*)Ks + rnd * 4096 + w * 1024);
      load_lds16((const char*)Vg + (size_t)row * 2048 + (size_t)t0 * 2 + scol, (char*)Vs + rnd * 4096 + w * 1024);
    }
    // bias fragment loads (overlap with staging)
    float bvals[4][4];
    bool diag = (t0 == q0);
#pragma unroll
    for (int nf = 0; nf < 4; ++nf) {
      int ck = t0 + nf * 16 + lr;
#pragma unroll
      for (int r = 0; r < 4; ++r)
        bvals[nf][r] = biasg[(size_t)rq[r] * 1024 + ck];
    }
    __syncthreads();

    // S = Q K^T (scales pre-folded into Q)
    f32x4 s[4];
#pragma unroll
    for (int nf = 0; nf < 4; ++nf) {
      int key = nf * 16 + lr;
      int base = key * 128;
      bf16x8 bk0 = *(const bf16x8*)((const char*)Ks + base + ((g * 16) ^ ((key & 7) << 4)));
      bf16x8 bk1 = *(const bf16x8*)((const char*)Ks + base + ((64 + g * 16) ^ ((key & 7) << 4)));
      f32x4 a = (f32x4){0.f, 0.f, 0.f, 0.f};
      a = __builtin_amdgcn_mfma_f32_16x16x32_bf16(aq0, bk0, a, 0, 0, 0);
      a = __builtin_amdgcn_mfma_f32_16x16x32_bf16(aq1, bk1, a, 0, 0, 0);
      s[nf] = a;
    }

    // bias + mask + online softmax
    float pv[4][4];
    float rmax[4];
#pragma unroll
    for (int r = 0; r < 4; ++r) rmax[r] = -1e30f;
#pragma unroll
    for (int nf = 0; nf < 4; ++nf) {
      int ck = t0 + nf * 16 + lr;
#pragma unroll
      for (int r = 0; r < 4; ++r) {
        float sv = s[nf][r] + bvals[nf][r];
        if (diag && ck > rq[r]) sv = -1e30f;
        pv[nf][r] = sv;
        rmax[r] = fmaxf(rmax[r], sv);
      }
    }
#pragma unroll
    for (int d = 1; d < 16; d <<= 1)
#pragma unroll
      for (int r = 0; r < 4; ++r) rmax[r] = fmaxf(rmax[r], __shfl_xor(rmax[r], d));
    float sf[4];
#pragma unroll
    for (int r = 0; r < 4; ++r) {
      float mn = fmaxf(mrow[r], rmax[r]);
      sf[r] = exp2f((mrow[r] - mn) * LOG2E);
      mrow[r] = mn;
    }
    float rsum[4] = {0.f, 0.f, 0.f, 0.f};
#pragma unroll
    for (int nf = 0; nf < 4; ++nf)
#pragma unroll
      for (int r = 0; r < 4; ++r) {
        float p = exp2f((pv[nf][r] - mrow[r]) * LOG2E);
        pv[nf][r] = p; rsum[r] += p;
      }
#pragma unroll
    for (int d = 1; d < 16; d <<= 1)
#pragma unroll
      for (int r = 0; r < 4; ++r) rsum[r] += __shfl_xor(rsum[r], d);
#pragma unroll
    for (int r = 0; r < 4; ++r) lsum[r] = lsum[r] * sf[r] + rsum[r];
#pragma unroll
    for (int df = 0; df < 4; ++df) {
      f32x4 o = oacc[df];
#pragma unroll
      for (int r = 0; r < 4; ++r) o[r] *= sf[r];
      oacc[df] = o;
    }

    // P -> per-wave LDS (padded stride 72), then PV
    u16* Pw = &Ps[w][0];
#pragma unroll
    for (int nf = 0; nf < 4; ++nf)
#pragma unroll
      for (int r = 0; r < 4; ++r)
        Pw[(g * 4 + r) * 72 + nf * 16 + lr] = f2bf(pv[nf][r]);
    bf16x8 pa0 = *(const bf16x8*)(Pw + lr * 72 + g * 8);
    bf16x8 pa1 = *(const bf16x8*)(Pw + lr * 72 + 32 + g * 8);
#pragma unroll
    for (int df = 0; df < 4; ++df) {
      int d = df * 16 + lr;
      int base = d * 128;
      bf16x8 bv0 = *(const bf16x8*)((const char*)Vs + base + ((g * 16) ^ ((d & 7) << 4)));
      bf16x8 bv1 = *(const bf16x8*)((const char*)Vs + base + ((64 + g * 16) ^ ((d & 7) << 4)));
      oacc[df] = __builtin_amdgcn_mfma_f32_16x16x32_bf16(pa0, bv0, oacc[df], 0, 0, 0);
      oacc[df] = __builtin_amdgcn_mfma_f32_16x16x32_bf16(pa1, bv1, oacc[df], 0, 0, 0);
    }
    __syncthreads();
  }

  // finalize: O /= lsum, write Y (B,T,H*64) bf16
#pragma unroll
  for (int r = 0; r < 4; ++r) lsum[r] = 1.0f / lsum[r];
#pragma unroll
  for (int df = 0; df < 4; ++df)
#pragma unroll
    for (int r = 0; r < 4; ++r) {
      float o = oacc[df][r] * lsum[r];
      Yb[((size_t)b * 1024 + rq[r]) * 1024 + h * 64 + df * 16 + lr] = f2bf(o);
    }
}

extern "C" void kernel_launch(void* const* d_in, const int* in_sizes, int n_in,
                              void* d_out, int out_size, void* d_ws, size_t ws_size,
                              hipStream_t stream) {
  const float* x     = (const float*)d_in[0];
  const float* enc   = (const float*)d_in[1];
  const float* freqs = (const float*)d_in[2];
  const float* bias  = (const float*)d_in[3];
  const float* Wq    = (const float*)d_in[4];
  const float* Wk    = (const float*)d_in[5];
  const float* Wv    = (const float*)d_in[6];
  const float* Wo    = (const float*)d_in[7];
  const float* qs    = (const float*)d_in[8];
  const float* ks    = (const float*)d_in[9];

  char* ws = (char*)d_ws;
  size_t off = 0;
  auto alloc = [&](size_t bytes) { char* p = ws + off; off += (bytes + 255) & ~(size_t)255; return p; };
  u16*   xb  = (u16*)alloc(8388608);    // x bf16 (4096 x 1024)
  u16*   eb  = (u16*)alloc(8388608);    // enc bf16
  u16*   WqT = (u16*)alloc(2097152);    // (1024 x 1024)
  u16*   WkT = (u16*)alloc(1048576);    // (512 x 1024)
  u16*   WvT = (u16*)alloc(1048576);
  u16*   WoT = (u16*)alloc(2097152);
  float* qr  = (float*)alloc(16777216); // q raw f32 (4096 x 1024)
  float* kr  = (float*)alloc(8388608);  // k raw (4096 x 512)
  float* vr  = (float*)alloc(8388608);
  u16*   Qb  = (u16*)alloc(8388608);    // (B,H,T,D) bf16
  u16*   Kbb = (u16*)alloc(4194304);    // (B,KV,T,D)
  u16*   Vtb = (u16*)alloc(4194304);    // (B,KV,D,T)
  u16*   Yb  = (u16*)xb;                // alias: xb dead after QKV GEMM

  cast_bf16_kernel<<<2048, 256, 0, stream>>>(x, xb, 1048576);
  cast_bf16_kernel<<<2048, 256, 0, stream>>>(enc, eb, 1048576);
  transpose_cast_kernel<<<dim3(32, 32), dim3(32, 8), 0, stream>>>(Wq, WqT, 1024, 1024);
  transpose_cast_kernel<<<dim3(16, 32), dim3(32, 8), 0, stream>>>(Wk, WkT, 1024, 512);
  transpose_cast_kernel<<<dim3(16, 32), dim3(32, 8), 0, stream>>>(Wv, WvT, 1024, 512);
  transpose_cast_kernel<<<dim3(32, 32), dim3(32, 8), 0, stream>>>(Wo, WoT, 1024, 1024);

  gemm_qkv_kernel<<<dim3(32, 8, 3), 256, 0, stream>>>(xb, eb, WqT, WkT, WvT, qr, kr, vr);

  // q folded scale: default_scale/QK_NORM_SCALE * default_scale = 0.125*0.125/10
  epilogue_qk_kernel<<<16384, 256, 0, stream>>>(qr, qs, freqs, Qb, 4, 0.0015625f);
  epilogue_qk_kernel<<<8192, 256, 0, stream>>>(kr, ks, freqs, Kbb, 3, 1.0f);
  epilogue_v_kernel<<<512, 256, 0, stream>>>(vr, freqs, Vtb);

  attn_kernel<<<dim3(16, 64), 256, 0, stream>>>(Qb, Kbb, Vtb, bias, Yb);

  gemm_out_kernel<<<dim3(32, 8), 256, 0, stream>>>(Yb, WoT, (float*)d_out);
}

// Round 2
// 135.853 us; speedup vs baseline: 1.2006x; 1.2006x over previous
//
#include <hip/hip_runtime.h>

typedef unsigned short u16;
typedef __attribute__((ext_vector_type(8))) __bf16 bf16x8;
typedef __attribute__((ext_vector_type(4))) float f32x4;

#define LOG2E 1.44269504088896f

__device__ __forceinline__ u16 f2bf(float f) {
  union { float f; unsigned u; } c; c.f = f;
  unsigned u = c.u;
  return (u16)((u + 0x7fffu + ((u >> 16) & 1u)) >> 16);
}

__device__ __forceinline__ void load_lds16(const void* g, void* l) {
  __builtin_amdgcn_global_load_lds((const __attribute__((address_space(1))) unsigned int*)g,
                                   (__attribute__((address_space(3))) unsigned int*)l, 16, 0, 0);
}

// ---------------- cast f32 -> bf16 (x and enc fused) ----------------
__global__ void cast2_kernel(const float* __restrict__ a, const float* __restrict__ b,
                             u16* __restrict__ oa, u16* __restrict__ ob, int n4each) {
  int stride = gridDim.x * blockDim.x;
  for (int i = blockIdx.x * blockDim.x + threadIdx.x; i < 2 * n4each; i += stride) {
    const float4* src; ushort4* dst; int j;
    if (i < n4each) { src = (const float4*)a; dst = (ushort4*)oa; j = i; }
    else            { src = (const float4*)b; dst = (ushort4*)ob; j = i - n4each; }
    float4 v = src[j];
    ushort4 o;
    o.x = f2bf(v.x); o.y = f2bf(v.y); o.z = f2bf(v.z); o.w = f2bf(v.w);
    dst[j] = o;
  }
}

// ---------------- transpose + cast all 4 weights: in (1024 x C) f32 -> out (C x 1024) bf16 ----------------
__global__ void transpose_cast4_kernel(const float* __restrict__ Wq, const float* __restrict__ Wk,
                                       const float* __restrict__ Wv, const float* __restrict__ Wo,
                                       u16* __restrict__ WqT, u16* __restrict__ WkT,
                                       u16* __restrict__ WvT, u16* __restrict__ WoT) {
  __shared__ float tile[32][33];
  const float* in; u16* out; int C;
  int z = blockIdx.z;
  if (z == 0)      { in = Wq; out = WqT; C = 1024; }
  else if (z == 1) { in = Wk; out = WkT; C = 512; }
  else if (z == 2) { in = Wv; out = WvT; C = 512; }
  else             { in = Wo; out = WoT; C = 1024; }
  const int R = 1024;
  int c0 = blockIdx.x * 32, r0 = blockIdx.y * 32;
  if (c0 >= C) return;
  int tx = threadIdx.x, ty = threadIdx.y; // (32,8)
#pragma unroll
  for (int i = 0; i < 4; ++i)
    tile[ty + 8 * i][tx] = in[(size_t)(r0 + ty + 8 * i) * C + c0 + tx];
  __syncthreads();
#pragma unroll
  for (int i = 0; i < 4; ++i)
    out[(size_t)(c0 + ty + 8 * i) * R + r0 + tx] = f2bf(tile[tx][ty + 8 * i]);
}

// ---------------- 128x128 bf16 B^T GEMM body (BK=64, swizzled LDS) ----------------
__device__ __forceinline__ void gemm128_body(const u16* A, const u16* Bt, float* C,
                                             int N, int K, u16* As, u16* Bs) {
  int tid = threadIdx.x;
  int w = tid >> 6, l = tid & 63;
  int g = l >> 4, lr = l & 15;
  int m0 = blockIdx.x * 128, n0 = blockIdx.y * 128;
  int wr = w >> 1, wc = w & 1;
  f32x4 acc[4][4];
#pragma unroll
  for (int m = 0; m < 4; ++m)
#pragma unroll
    for (int n = 0; n < 4; ++n) acc[m][n] = (f32x4){0.f, 0.f, 0.f, 0.f};

  for (int k0 = 0; k0 < K; k0 += 64) {
#pragma unroll
    for (int rnd = 0; rnd < 4; ++rnd) {
      int bidx = rnd * 4096 + w * 1024 + l * 16;
      int row = bidx >> 7, colb = bidx & 127;
      int scol = colb ^ ((row & 7) << 4);
      load_lds16((const char*)A + ((size_t)(m0 + row) * K + k0) * 2 + scol,
                 (char*)As + rnd * 4096 + w * 1024);
      load_lds16((const char*)Bt + ((size_t)(n0 + row) * K + k0) * 2 + scol,
                 (char*)Bs + rnd * 4096 + w * 1024);
    }
    __syncthreads();
    bf16x8 af[4][2], bfr[4][2];
#pragma unroll
    for (int m = 0; m < 4; ++m) {
      int ra = wr * 64 + m * 16 + lr;
      int rb = wc * 64 + m * 16 + lr;
#pragma unroll
      for (int kf = 0; kf < 2; ++kf) {
        af[m][kf]  = *(const bf16x8*)((const char*)As + ra * 128 + ((kf * 64 + g * 16) ^ ((ra & 7) << 4)));
        bfr[m][kf] = *(const bf16x8*)((const char*)Bs + rb * 128 + ((kf * 64 + g * 16) ^ ((rb & 7) << 4)));
      }
    }
#pragma unroll
    for (int m = 0; m < 4; ++m)
#pragma unroll
      for (int n = 0; n < 4; ++n) {
        acc[m][n] = __builtin_amdgcn_mfma_f32_16x16x32_bf16(af[m][0], bfr[n][0], acc[m][n], 0, 0, 0);
        acc[m][n] = __builtin_amdgcn_mfma_f32_16x16x32_bf16(af[m][1], bfr[n][1], acc[m][n], 0, 0, 0);
      }
    __syncthreads();
  }
#pragma unroll
  for (int m = 0; m < 4; ++m)
#pragma unroll
    for (int n = 0; n < 4; ++n) {
      int row = m0 + wr * 64 + m * 16 + g * 4;
      int col = n0 + wc * 64 + n * 16 + lr;
#pragma unroll
      for (int r = 0; r < 4; ++r)
        C[(size_t)(row + r) * N + col] = acc[m][n][r];
    }
}

__global__ __launch_bounds__(256, 2) void gemm_qkv_kernel(const u16* xb, const u16* eb,
                                                          const u16* WqT, const u16* WkT, const u16* WvT,
                                                          float* qr, float* kr, float* vr) {
  __shared__ __align__(16) u16 As[128 * 64];
  __shared__ __align__(16) u16 Bs[128 * 64];
  int z = blockIdx.z;
  const u16* A; const u16* Bt; float* C; int N;
  if (z == 0)      { A = xb; Bt = WqT; C = qr; N = 1024; }
  else if (z == 1) { A = eb; Bt = WkT; C = kr; N = 512; }
  else             { A = eb; Bt = WvT; C = vr; N = 512; }
  if ((int)blockIdx.y * 128 >= N) return;
  gemm128_body(A, Bt, C, N, 1024, As, Bs);
}

__global__ __launch_bounds__(256, 2) void gemm_out_kernel(const u16* Yb, const u16* WoT, float* out) {
  __shared__ __align__(16) u16 As[128 * 64];
  __shared__ __align__(16) u16 Bs[128 * 64];
  gemm128_body(Yb, WoT, out, 1024, 1024, As, Bs);
}

// ---------------- Q+K epilogue (fused): l2norm + scale + rope + store (B,heads,T,64) bf16 ----------------
__global__ void epilogue_qk2_kernel(const float* __restrict__ qr, const float* __restrict__ kr,
                                    const float* __restrict__ qscale, const float* __restrict__ kscale,
                                    const float* __restrict__ freqs,
                                    u16* __restrict__ Qb, u16* __restrict__ Kb) {
  int unit = blockIdx.x * 4 + (threadIdx.x >> 6);
  int lane = threadIdx.x & 63;
  const float* raw; const float* scale; u16* out; int hshift; float final_scale;
  if (unit < 65536) { raw = qr; scale = qscale; out = Qb; hshift = 4; final_scale = 0.0015625f; }
  else { unit -= 65536; raw = kr; scale = kscale; out = Kb; hshift = 3; final_scale = 1.0f; }
  int nheads = 1 << hshift;
  int hd = unit & (nheads - 1);
  int row = unit >> hshift;        // b*1024 + t
  int t = row & 1023;
  int b = row >> 10;
  float v = raw[(size_t)row * (nheads * 64) + hd * 64 + lane];
  float ss = v * v;
#pragma unroll
  for (int d = 1; d < 64; d <<= 1) ss += __shfl_xor(ss, d);
  float inv = 1.0f / fmaxf(sqrtf(ss), 1e-12f);
  v = v * inv * scale[lane];
  float f = (lane < 32) ? freqs[t * 32 + lane] : 0.0f;
  float sn, cs;
  sincosf(f, &sn, &cs);
  float partner = __shfl_xor(v, 1);
  float rot = (lane & 1) ? partner : -partner;
  float vrot = v * cs + rot * sn;
  if (lane < 32) v = vrot;
  v *= final_scale;
  out[(((size_t)b * nheads + hd) * 1024 + t) * 64 + lane] = f2bf(v);
}

// ---------------- V epilogue: rope + store transposed (B,KV,D,T) bf16 ----------------
__global__ void epilogue_v_kernel(const float* __restrict__ v_raw, const float* __restrict__ freqs,
                                  u16* __restrict__ Vt) {
  __shared__ __align__(16) u16 tile[64][72];
  int blk = blockIdx.x;
  int t0 = (blk & 15) * 64;
  int kvg = blk >> 4;            // b*8 + kv
  int kvv = kvg & 7;
  int bb = kvg >> 3;
  int tid = threadIdx.x;
  int tl = tid >> 2;             // token local 0..63
  int dq = (tid & 3) * 16;       // dim base
  int t = t0 + tl;
  const float* src = v_raw + ((size_t)(bb * 1024 + t)) * 512 + kvv * 64 + dq;
  float x[16];
#pragma unroll
  for (int i = 0; i < 4; ++i) {
    float4 q = *(const float4*)(src + i * 4);
    x[i * 4 + 0] = q.x; x[i * 4 + 1] = q.y; x[i * 4 + 2] = q.z; x[i * 4 + 3] = q.w;
  }
  if (dq < 32) {
#pragma unroll
    for (int j = 0; j < 8; ++j) {
      int d = dq + 2 * j;
      float f = freqs[t * 32 + d];
      float sn, cs; sincosf(f, &sn, &cs);
      float e = x[2 * j], o = x[2 * j + 1];
      x[2 * j]     = e * cs - o * sn;
      x[2 * j + 1] = o * cs + e * sn;
    }
  }
#pragma unroll
  for (int i = 0; i < 16; ++i) tile[dq + i][tl] = f2bf(x[i]);
  __syncthreads();
#pragma unroll
  for (int rnd = 0; rnd < 2; ++rnd) {
    int chunk = rnd * 256 + tid;
    int drow = chunk >> 3, c8 = chunk & 7;
    bf16x8 val = *(const bf16x8*)((const char*)&tile[0][0] + drow * 144 + c8 * 16);
    *(bf16x8*)(Vt + ((size_t)kvg * 64 + drow) * 1024 + t0 + c8 * 8) = val;
  }
}

// ---------------- flash attention: causal-pair balanced + 2-phase pipeline ----------------
struct AState {
  float m[4];
  float lsum[4];
  f32x4 o[4];
};

__device__ __forceinline__ void attn_tile(const u16* Ksb, const u16* Vsb, u16* Pw,
                                          bf16x8 aq0, bf16x8 aq1,
                                          const float (&bv)[4][4], AState& st,
                                          bool diag, int t0, const int (&rq)[4],
                                          int g, int lr) {
  // S = Q K^T (scales pre-folded into Q)
  f32x4 s[4];
#pragma unroll
  for (int nf = 0; nf < 4; ++nf) {
    int key = nf * 16 + lr;
    int base = key * 128;
    bf16x8 bk0 = *(const bf16x8*)((const char*)Ksb + base + ((g * 16) ^ ((key & 7) << 4)));
    bf16x8 bk1 = *(const bf16x8*)((const char*)Ksb + base + ((64 + g * 16) ^ ((key & 7) << 4)));
    f32x4 a = (f32x4){0.f, 0.f, 0.f, 0.f};
    a = __builtin_amdgcn_mfma_f32_16x16x32_bf16(aq0, bk0, a, 0, 0, 0);
    a = __builtin_amdgcn_mfma_f32_16x16x32_bf16(aq1, bk1, a, 0, 0, 0);
    s[nf] = a;
  }
  // bias + mask + online softmax
  float pv[4][4];
  float rmax[4];
#pragma unroll
  for (int r = 0; r < 4; ++r) rmax[r] = -1e30f;
#pragma unroll
  for (int nf = 0; nf < 4; ++nf) {
    int ck = t0 + nf * 16 + lr;
#pragma unroll
    for (int r = 0; r < 4; ++r) {
      float sv = s[nf][r] + bv[nf][r];
      if (diag && ck > rq[r]) sv = -1e30f;
      pv[nf][r] = sv;
      rmax[r] = fmaxf(rmax[r], sv);
    }
  }
#pragma unroll
  for (int d = 1; d < 16; d <<= 1)
#pragma unroll
    for (int r = 0; r < 4; ++r) rmax[r] = fmaxf(rmax[r], __shfl_xor(rmax[r], d));
  float sf[4];
#pragma unroll
  for (int r = 0; r < 4; ++r) {
    float mn = fmaxf(st.m[r], rmax[r]);
    sf[r] = exp2f((st.m[r] - mn) * LOG2E);
    st.m[r] = mn;
  }
  float rsum[4] = {0.f, 0.f, 0.f, 0.f};
#pragma unroll
  for (int nf = 0; nf < 4; ++nf)
#pragma unroll
    for (int r = 0; r < 4; ++r) {
      float p = exp2f((pv[nf][r] - st.m[r]) * LOG2E);
      pv[nf][r] = p; rsum[r] += p;
    }
#pragma unroll
  for (int d = 1; d < 16; d <<= 1)
#pragma unroll
    for (int r = 0; r < 4; ++r) rsum[r] += __shfl_xor(rsum[r], d);
#pragma unroll
  for (int r = 0; r < 4; ++r) st.lsum[r] = st.lsum[r] * sf[r] + rsum[r];
#pragma unroll
  for (int df = 0; df < 4; ++df) {
    f32x4 o = st.o[df];
#pragma unroll
    for (int r = 0; r < 4; ++r) o[r] *= sf[r];
    st.o[df] = o;
  }
  // P -> per-wave LDS (padded stride 72), then PV
#pragma unroll
  for (int nf = 0; nf < 4; ++nf)
#pragma unroll
    for (int r = 0; r < 4; ++r)
      Pw[(g * 4 + r) * 72 + nf * 16 + lr] = f2bf(pv[nf][r]);
  bf16x8 pa0 = *(const bf16x8*)(Pw + lr * 72 + g * 8);
  bf16x8 pa1 = *(const bf16x8*)(Pw + lr * 72 + 32 + g * 8);
#pragma unroll
  for (int df = 0; df < 4; ++df) {
    int d = df * 16 + lr;
    int base = d * 128;
    bf16x8 bv0 = *(const bf16x8*)((const char*)Vsb + base + ((g * 16) ^ ((d & 7) << 4)));
    bf16x8 bv1 = *(const bf16x8*)((const char*)Vsb + base + ((64 + g * 16) ^ ((d & 7) << 4)));
    st.o[df] = __builtin_amdgcn_mfma_f32_16x16x32_bf16(pa0, bv0, st.o[df], 0, 0, 0);
    st.o[df] = __builtin_amdgcn_mfma_f32_16x16x32_bf16(pa1, bv1, st.o[df], 0, 0, 0);
  }
}

__global__ __launch_bounds__(256, 2) void attn_kernel(const u16* __restrict__ Qb, const u16* __restrict__ Kb,
                                                      const u16* __restrict__ Vtb, const float* __restrict__ bias,
                                                      u16* __restrict__ Yb) {
  __shared__ __align__(16) u16 Ks[2][64 * 64];
  __shared__ __align__(16) u16 Vs[2][64 * 64];
  __shared__ __align__(16) u16 Ps[4][16 * 72];
  int tid = threadIdx.x;
  int w = tid >> 6, l = tid & 63;
  int g = l >> 4, lr = l & 15;
  int p = blockIdx.x;            // 0..7 : q-tile pair (p, 15-p)
  int y = blockIdx.y;            // h*4 + b  (h-major for bias L2 locality)
  int h = y >> 2, b = y & 3, kv = h & 7;
  int qa0 = p * 64, qb0 = (15 - p) * 64;

  const u16* QrowA = Qb + ((size_t)(b * 16 + h) * 1024 + qa0 + w * 16 + lr) * 64;
  const u16* QrowB = Qb + ((size_t)(b * 16 + h) * 1024 + qb0 + w * 16 + lr) * 64;
  bf16x8 aqA0 = *(const bf16x8*)(QrowA + g * 8);
  bf16x8 aqA1 = *(const bf16x8*)(QrowA + 32 + g * 8);
  bf16x8 aqB0 = *(const bf16x8*)(QrowB + g * 8);
  bf16x8 aqB1 = *(const bf16x8*)(QrowB + 32 + g * 8);
  const u16* Kg = Kb + (size_t)(b * 8 + kv) * 1024 * 64;
  const u16* Vg = Vtb + (size_t)(b * 8 + kv) * 64 * 1024;
  const float* biasg = bias + (size_t)h * 1024 * 1024;

  AState stA, stB;
#pragma unroll
  for (int r = 0; r < 4; ++r) {
    stA.m[r] = -1e30f; stA.lsum[r] = 0.f;
    stB.m[r] = -1e30f; stB.lsum[r] = 0.f;
  }
#pragma unroll
  for (int df = 0; df < 4; ++df) {
    stA.o[df] = (f32x4){0.f, 0.f, 0.f, 0.f};
    stB.o[df] = (f32x4){0.f, 0.f, 0.f, 0.f};
  }
  int rqa[4], rqb[4];
#pragma unroll
  for (int r = 0; r < 4; ++r) {
    rqa[r] = qa0 + w * 16 + g * 4 + r;
    rqb[r] = qb0 + w * 16 + g * 4 + r;
  }
  u16* Pw = &Ps[w][0];

  auto stage = [&](int bufsel, int t0) {
#pragma unroll
    for (int rnd = 0; rnd < 2; ++rnd) {
      int bidx = rnd * 4096 + w * 1024 + l * 16;
      int row = bidx >> 7, colb = bidx & 127;
      int scol = colb ^ ((row & 7) << 4);
      load_lds16((const char*)Kg + (size_t)(t0 + row) * 128 + scol,
                 (char*)&Ks[bufsel][0] + rnd * 4096 + w * 1024);
      load_lds16((const char*)Vg + (size_t)row * 2048 + (size_t)t0 * 2 + scol,
                 (char*)&Vs[bufsel][0] + rnd * 4096 + w * 1024);
    }
  };

  float bA_c[4][4], bB_c[4][4], bA_n[4][4], bB_n[4][4];
  auto bias_load = [&](float (&dst)[4][4], const int (&rq)[4], int t0) {
#pragma unroll
    for (int nf = 0; nf < 4; ++nf) {
      int ck = t0 + nf * 16 + lr;
#pragma unroll
      for (int r = 0; r < 4; ++r)
        dst[nf][r] = biasg[(size_t)rq[r] * 1024 + ck];
    }
  };

  // prologue: stage tile 0 + bias tile 0 for both q-tiles
  stage(0, 0);
  bias_load(bB_c, rqb, 0);
  bias_load(bA_c, rqa, 0);
  __syncthreads();

  for (int t0 = 0; t0 <= qb0; t0 += 64) {
    int cur = (t0 >> 6) & 1;
    int tn = t0 + 64;
    bool hnB = tn <= qb0;
    bool hnA = tn <= qa0;
    // issue next tile's staging + bias loads BEFORE compute (latency hides under MFMA/softmax)
    if (hnB) {
      stage(cur ^ 1, tn);
      bias_load(bB_n, rqb, tn);
      if (hnA) bias_load(bA_n, rqa, tn);
    }
    attn_tile(&Ks[cur][0], &Vs[cur][0], Pw, aqB0, aqB1, bB_c, stB, t0 == qb0, t0, rqb, g, lr);
    if (t0 <= qa0)
      attn_tile(&Ks[cur][0], &Vs[cur][0], Pw, aqA0, aqA1, bA_c, stA, t0 == qa0, t0, rqa, g, lr);
    __syncthreads();   // drains stage(next) vmcnt AFTER compute
    if (hnB) {
#pragma unroll
      for (int nf = 0; nf < 4; ++nf)
#pragma unroll
        for (int r = 0; r < 4; ++r) bB_c[nf][r] = bB_n[nf][r];
      if (hnA) {
#pragma unroll
        for (int nf = 0; nf < 4; ++nf)
#pragma unroll
          for (int r = 0; r < 4; ++r) bA_c[nf][r] = bA_n[nf][r];
      }
    }
  }

  // finalize both q-tiles: O /= lsum, write Y (B,T,H*64) bf16
  float invA[4], invB[4];
#pragma unroll
  for (int r = 0; r < 4; ++r) { invA[r] = 1.0f / stA.lsum[r]; invB[r] = 1.0f / stB.lsum[r]; }
#pragma unroll
  for (int df = 0; df < 4; ++df)
#pragma unroll
    for (int r = 0; r < 4; ++r) {
      Yb[((size_t)b * 1024 + rqa[r]) * 1024 + h * 64 + df * 16 + lr] = f2bf(stA.o[df][r] * invA[r]);
      Yb[((size_t)b * 1024 + rqb[r]) * 1024 + h * 64 + df * 16 + lr] = f2bf(stB.o[df][r] * invB[r]);
    }
}

extern "C" void kernel_launch(void* const* d_in, const int* in_sizes, int n_in,
                              void* d_out, int out_size, void* d_ws, size_t ws_size,
                              hipStream_t stream) {
  const float* x     = (const float*)d_in[0];
  const float* enc   = (const float*)d_in[1];
  const float* freqs = (const float*)d_in[2];
  const float* bias  = (const float*)d_in[3];
  const float* Wq    = (const float*)d_in[4];
  const float* Wk    = (const float*)d_in[5];
  const float* Wv    = (const float*)d_in[6];
  const float* Wo    = (const float*)d_in[7];
  const float* qs    = (const float*)d_in[8];
  const float* ks    = (const float*)d_in[9];

  char* ws = (char*)d_ws;
  size_t off = 0;
  auto alloc = [&](size_t bytes) { char* p = ws + off; off += (bytes + 255) & ~(size_t)255; return p; };
  u16*   xb  = (u16*)alloc(8388608);    // x bf16 (4096 x 1024)
  u16*   eb  = (u16*)alloc(8388608);    // enc bf16
  u16*   WqT = (u16*)alloc(2097152);    // (1024 x 1024)
  u16*   WkT = (u16*)alloc(1048576);    // (512 x 1024)
  u16*   WvT = (u16*)alloc(1048576);
  u16*   WoT = (u16*)alloc(2097152);
  float* qr  = (float*)alloc(16777216); // q raw f32 (4096 x 1024)
  float* kr  = (float*)alloc(8388608);  // k raw (4096 x 512)
  float* vr  = (float*)alloc(8388608);
  u16*   Qb  = (u16*)alloc(8388608);    // (B,H,T,D) bf16
  u16*   Kbb = (u16*)alloc(4194304);    // (B,KV,T,D)
  u16*   Vtb = (u16*)alloc(4194304);    // (B,KV,D,T)
  u16*   Yb  = (u16*)xb;                // alias: xb dead after QKV GEMM

  cast2_kernel<<<2048, 256, 0, stream>>>(x, enc, xb, eb, 1048576);
  transpose_cast4_kernel<<<dim3(32, 32, 4), dim3(32, 8), 0, stream>>>(Wq, Wk, Wv, Wo, WqT, WkT, WvT, WoT);

  gemm_qkv_kernel<<<dim3(32, 8, 3), 256, 0, stream>>>(xb, eb, WqT, WkT, WvT, qr, kr, vr);

  // q folded scale: default_scale/QK_NORM_SCALE * default_scale = 0.125*0.125/10
  epilogue_qk2_kernel<<<24576, 256, 0, stream>>>(qr, kr, qs, ks, freqs, Qb, Kbb);
  epilogue_v_kernel<<<512, 256, 0, stream>>>(vr, freqs, Vtb);

  attn_kernel<<<dim3(8, 64), 256, 0, stream>>>(Qb, Kbb, Vtb, bias, Yb);

  gemm_out_kernel<<<dim3(32, 8), 256, 0, stream>>>(Yb, WoT, (float*)d_out);
}